// Round 14
// baseline (189.430 us; speedup 1.0000x reference)
//
#include <hip/hip_runtime.h>
#include <hip/hip_bf16.h>
#include <stdint.h>

// Problem constants
#define B_   4
#define L_   1024
#define D_   1024
#define H_   16
#define HD_  64
#define E_   16384
#define BH_  (B_*H_)    // 64
#define BL_  (B_*L_)    // 4096

typedef __bf16 bf16;
typedef __bf16 bf16x8 __attribute__((ext_vector_type(8)));
typedef float  f32x4  __attribute__((ext_vector_type(4)));
typedef unsigned short u16x8 __attribute__((ext_vector_type(8)));

#if __has_builtin(__builtin_amdgcn_exp2f)
#define EXP2F(x) __builtin_amdgcn_exp2f(x)
#else
#define EXP2F(x) exp2f(x)
#endif

// scale folded into Q at the QKV epilogue: 1/sqrt(64) * log2(e)
#define QSCALE 0.18033688011112042f

// Single-barrier pipeline step (gemm_qkv; measured best there in r12).
#define PIPE_SYNC() do {                                   \
    asm volatile("s_waitcnt vmcnt(0)" ::: "memory");       \
    __builtin_amdgcn_s_barrier();                          \
    asm volatile("" ::: "memory");                         \
  } while (0)

// async global->LDS, 16B per lane. lds_dst must be wave-uniform; HW adds lane*16.
__device__ __forceinline__ void gload_lds16(const bf16* gsrc, bf16* lds_dst) {
  __builtin_amdgcn_global_load_lds(
      (const __attribute__((address_space(1))) unsigned int*)gsrc,
      (__attribute__((address_space(3))) unsigned int*)lds_dst,
      16, 0, 0);
}

// ---------------------------------------------------------------------------
// Node 1: canonicalization + adj ZEROING + dtype detection (round 11 form).
__global__ __launch_bounds__(256) void k_castall(
    const void* __restrict__ x, const void* __restrict__ wq,
    const void* __restrict__ wo, const void* __restrict__ bq,
    const void* __restrict__ bo,
    unsigned long long* __restrict__ adj,
    bf16* __restrict__ xb, bf16* __restrict__ wqb, bf16* __restrict__ wob,
    float* __restrict__ bqf, float* __restrict__ bof,
    unsigned int* __restrict__ flag_out) {
  const int t = threadIdx.x;

  if (blockIdx.x == 0 && t == 0) *flag_out = 0u;
  if (blockIdx.x < 64) adj[blockIdx.x * 256 + t] = 0ull;

  bool lf = false;
  {
    u16x8 u = *(const u16x8*)((const unsigned short*)wq + (size_t)t * 8);
#pragma unroll
    for (int q = 0; q < 8; ++q) lf |= (((u[q] >> 7) & 0xFF) >= 200);
  }
  const bool f = __any(lf);
  if (blockIdx.x == 0 && t == 0 && f) *flag_out = 1u;

  const long e = ((long)blockIdx.x * 256 + t) * 8;
  const long N0 = 4l << 20, N1 = N0 + (3l << 20), N2 = N1 + (1l << 20);
  const void* src;
  bf16* d16 = nullptr; float* d32 = nullptr; long j;
  if (e < N0)      { src = x;  d16 = xb;  j = e; }
  else if (e < N1) { src = wq; d16 = wqb; j = e - N0; }
  else if (e < N2) { src = wo; d16 = wob; j = e - N1; }
  else {
    long b = e - N2;
    if (b < 3072)      { src = bq; d32 = bqf; j = b; }
    else if (b < 4096) { src = bo; d32 = bof; j = b - 3072; }
    else return;
  }
  if (d16) {
    bf16x8 v;
    if (f) {
      const float* s = (const float*)src + j;
#pragma unroll
      for (int q = 0; q < 8; ++q) v[q] = (bf16)s[q];
    } else {
      v = *(const bf16x8*)((const bf16*)src + j);
    }
    *(bf16x8*)(d16 + j) = v;
  } else {
    if (f) {
      const f32x4* s = (const f32x4*)((const float*)src + j);
      f32x4 a = s[0], b2 = s[1];
      *(f32x4*)(d32 + j) = a;
      *((f32x4*)(d32 + j) + 1) = b2;
    } else {
      const bf16* s = (const bf16*)src + j;
#pragma unroll
      for (int q = 0; q < 8; ++q) d32[j + q] = (float)s[q];
    }
  }
}

// ---------------------------------------------------------------------------
// Node 2: QKV GEMM + adjacency build.
// Round-14: BK=64 (16 K-iterations instead of 32). Rationale: gemm_qkv is
// invariant at ~44.5us across occupancy/conflicts/reads-per-MFMA/barrier
// count (r6/r7/r12) -> the binder is a fixed ~500cy per-iteration overhead
// (stage-issue + wait + barrier skew) paid 32x. BK=64 pays it 16x; per-iter
// work doubles (2 chunks x {6 frag reads, 8 MFMA}); registers unchanged
// (af/bfv reused per chunk, acc stays 32) -> no spill risk.
// BK=64 rows are 128B == attn's row geometry: reuse attn's PROVEN
// conflict-free (row&7) XOR swizzle (pre-swizzled source col
// ((lane&7)^(lane>>3))*8; reads at psoff ^ (c<<6)).
// LDS 64KB -> 2 blocks/CU = 16 waves/CU (== current effective 15.4).
// Single-barrier PIPE_SYNC kept (r12: best for this kernel).
__global__ __launch_bounds__(512, 4) void k_gemm_qkv(
    const bf16* __restrict__ A, const bf16* __restrict__ W,
    const float* __restrict__ bias,
    const int* __restrict__ edges, unsigned long long* __restrict__ adj,
    bf16* __restrict__ qb, bf16* __restrict__ kb, bf16* __restrict__ vb) {
  constexpr int K = 1024;
  __shared__ __align__(16) bf16 As[2 * 8192];   // [buf][128 rows][64 cols]
  __shared__ __align__(16) bf16 Bs[2 * 8192];

  const int t = threadIdx.x;
  const int lane = t & 63, w = t >> 6;
  const int wm = w >> 1, wn = w & 1;          // 4x2 wave grid
  const int quad = lane >> 4, l16 = lane & 15;
  const int m0 = blockIdx.y * 128, n0 = blockIdx.x * 128;

  // adjacency build, load-balanced: every block handles <=1 edge per thread.
  {
    const int lbid = blockIdx.y * 24 + blockIdx.x;
    const int gid = t * 768 + lbid;
    if (gid < E_) {
      int a = edges[2 * gid], b = edges[2 * gid + 1];
      atomicOr(&adj[a * 16 + (b >> 6)], 1ull << (b & 63));
      atomicOr(&adj[b * 16 + (a >> 6)], 1ull << (a & 63));
    }
  }

  const bf16* Abase = A + m0 * K;
  const bf16* Wbase = W + n0 * K;

  // Staging: wave w covers rows w*8..w*8+7 per 8KB issue (lane l: row
  // w*8 + (l>>3), 16B slot l&7). Two issues per matrix (rows 0-63, 64-127).
  // Source pre-swizzled: scol = ((l&7) ^ (l>>3)) * 8 elems (row&7 == l>>3
  // for both issues since 64 = 0 mod 8).
  const int vr = lane >> 3;
  const int scol = ((lane & 7) ^ vr) * 8;
  const bf16* asrc0 = Abase + (w * 8 + vr) * K + scol;        // + it*64
  const bf16* asrc1 = Abase + (64 + w * 8 + vr) * K + scol;
  const bf16* wsrc0 = Wbase + (w * 8 + vr) * K + scol;
  const bf16* wsrc1 = Wbase + (64 + w * 8 + vr) * K + scol;

  // fragment read: row R (R&7 == l16&7), byte col c*64 + quad*16,
  // swizzled: ^ ((l16&7)<<4). psoff ^ (c<<6) (disjoint bits => XOR ok).
  const int psoff = (quad * 16) ^ ((l16 & 7) << 4);

  f32x4 acc[2][4] = {};

#define STAGE_AB(it1) do {                                          \
    const int bo_ = ((it1) & 1) * 8192;                             \
    gload_lds16(asrc0 + (it1) * 64, &As[bo_ + w * 512]);            \
    gload_lds16(asrc1 + (it1) * 64, &As[bo_ + 4096 + w * 512]);     \
    gload_lds16(wsrc0 + (it1) * 64, &Bs[bo_ + w * 512]);            \
    gload_lds16(wsrc1 + (it1) * 64, &Bs[bo_ + 4096 + w * 512]);     \
  } while (0)

  STAGE_AB(0);

#pragma unroll 1
  for (int it = 0; it < 16; ++it) {
    const int bo = (it & 1) * 8192;   // LDS offset only (address math)

    PIPE_SYNC();                      // stage(it) visible; buf^1 reads done
    if (it < 15) STAGE_AB(it + 1);    // write buf^1, safe after barrier

#pragma unroll
    for (int c = 0; c < 2; ++c) {
      const int fo = (psoff ^ (c << 6)) >> 1;
      bf16x8 af[2], bfv[4];
#pragma unroll
      for (int i = 0; i < 2; ++i)
        af[i] = *(const bf16x8*)&As[bo + (wm * 32 + i * 16 + l16) * 64 + fo];
#pragma unroll
      for (int j = 0; j < 4; ++j)
        bfv[j] = *(const bf16x8*)&Bs[bo + (wn * 64 + j * 16 + l16) * 64 + fo];
#pragma unroll
      for (int mi = 0; mi < 2; ++mi)
#pragma unroll
        for (int ni = 0; ni < 4; ++ni)
          acc[mi][ni] = __builtin_amdgcn_mfma_f32_16x16x32_bf16(
              af[mi], bfv[ni], acc[mi][ni], 0, 0, 0);
    }
  }
#undef STAGE_AB

  // Epilogue. C/D layout: col = lane&15, row = quad*4 + r.
#pragma unroll
  for (int ni = 0; ni < 4; ++ni) {
    int col = n0 + wn * 64 + ni * 16 + l16;
    float bv = bias[col];
    int which = col >> 10;
    int hcol = col & 1023;
    int h = hcol >> 6, hd = hcol & 63;
#pragma unroll
    for (int mi = 0; mi < 2; ++mi)
#pragma unroll
      for (int r = 0; r < 4; ++r) {
        int row = m0 + wm * 32 + mi * 16 + quad * 4 + r;
        int bb = row >> 10, l = row & 1023;
        int bh = bb * H_ + h;
        float v = acc[mi][ni][r] + bv;
        if (which == 0)      qb[(bh * L_ + l) * HD_ + hd] = (bf16)(v * QSCALE);
        else if (which == 1) kb[(bh * L_ + l) * HD_ + hd] = (bf16)v;
        else                 vb[(bh * HD_ + hd) * L_ + l] = (bf16)v;  // transposed
      }
  }
}

// ---------------------------------------------------------------------------
// Node 4: output projection GEMM, BK=64 (16 iters), 64x64 tiles, grid
// (16,64) = 1024 blocks. Two-barrier counted form (r12: best here).
// LDS 32KB -> 4 blocks/CU retained. Same attn-proven (row&7) swizzle.
__global__ __launch_bounds__(256, 4) void k_gemm_out(
    const bf16* __restrict__ A, const bf16* __restrict__ W,
    const float* __restrict__ bias, void* __restrict__ outv,
    const unsigned int* __restrict__ flag) {
  constexpr int K = 1024;
  __shared__ __align__(16) bf16 As[2 * 4096];   // [buf][64 rows][64 cols]
  __shared__ __align__(16) bf16 Bs[2 * 4096];

  const int t = threadIdx.x;
  const int lane = t & 63, w = t >> 6;
  const int wm = w >> 1, wn = w & 1;          // 2x2 wave grid
  const int quad = lane >> 4, l16 = lane & 15;
  const int m0 = blockIdx.y * 64, n0 = blockIdx.x * 64;

  const bf16* Abase = A + m0 * K;
  const bf16* Wbase = W + n0 * K;

  // Staging: 4 waves x 8 rows = 32 rows per 4KB issue; two issues per matrix.
  const int vr = lane >> 3;
  const int scol = ((lane & 7) ^ vr) * 8;
  const bf16* asrc0 = Abase + (w * 8 + vr) * K + scol;        // + it*64
  const bf16* asrc1 = Abase + (32 + w * 8 + vr) * K + scol;
  const bf16* wsrc0 = Wbase + (w * 8 + vr) * K + scol;
  const bf16* wsrc1 = Wbase + (32 + w * 8 + vr) * K + scol;

  const int psoff = (quad * 16) ^ ((l16 & 7) << 4);

  f32x4 acc[2][2] = {};

#define STAGE_O(it1) do {                                           \
    const int bo_ = ((it1) & 1) * 4096;                             \
    gload_lds16(asrc0 + (it1) * 64, &As[bo_ + w * 512]);            \
    gload_lds16(asrc1 + (it1) * 64, &As[bo_ + 2048 + w * 512]);     \
    gload_lds16(wsrc0 + (it1) * 64, &Bs[bo_ + w * 512]);            \
    gload_lds16(wsrc1 + (it1) * 64, &Bs[bo_ + 2048 + w * 512]);     \
  } while (0)

  STAGE_O(0);

#pragma unroll 1
  for (int it = 0; it < 16; ++it) {
    const int bo = (it & 1) * 4096;

    if (it < 15) STAGE_O(it + 1);

    // Retire stage(it) (4 ops); leave stage(it+1)'s 4 in flight.
    if (it < 15) asm volatile("s_waitcnt vmcnt(4)" ::: "memory");
    else         asm volatile("s_waitcnt vmcnt(0)" ::: "memory");
    __builtin_amdgcn_s_barrier();

#pragma unroll
    for (int c = 0; c < 2; ++c) {
      const int fo = (psoff ^ (c << 6)) >> 1;
      bf16x8 af[2], bfv[2];
#pragma unroll
      for (int i = 0; i < 2; ++i) {
        af[i]  = *(const bf16x8*)&As[bo + (wm * 32 + i * 16 + l16) * 64 + fo];
        bfv[i] = *(const bf16x8*)&Bs[bo + (wn * 32 + i * 16 + l16) * 64 + fo];
      }
#pragma unroll
      for (int mi = 0; mi < 2; ++mi)
#pragma unroll
        for (int ni = 0; ni < 2; ++ni)
          acc[mi][ni] = __builtin_amdgcn_mfma_f32_16x16x32_bf16(
              af[mi], bfv[ni], acc[mi][ni], 0, 0, 0);
    }
    __builtin_amdgcn_s_barrier();
  }
#undef STAGE_O

  // Epilogue. C/D layout: col = lane&15, row = quad*4 + r.
  const bool f32out = (*flag != 0);
#pragma unroll
  for (int ni = 0; ni < 2; ++ni) {
    int col = n0 + wn * 32 + ni * 16 + l16;
    float bv = bias[col];
#pragma unroll
    for (int mi = 0; mi < 2; ++mi)
#pragma unroll
      for (int r = 0; r < 4; ++r) {
        int row = m0 + wm * 32 + mi * 16 + quad * 4 + r;
        float v = acc[mi][ni][r] + bv;
        if (f32out) ((float*)outv)[row * 1024 + col] = v;
        else        ((bf16*)outv)[row * 1024 + col] = (bf16)v;
      }
  }
}

// ---------------------------------------------------------------------------
// Node 3: flash attention (round-13 form, unchanged — attn left top-5 with
// the shared-staging 8-wave geometry).
__global__ __launch_bounds__(512, 4) void k_attn(
    const bf16* __restrict__ qb, const bf16* __restrict__ kb,
    const bf16* __restrict__ vb, const unsigned long long* __restrict__ adj,
    bf16* __restrict__ aout) {
  __shared__ __align__(16) bf16 Ks[2 * 64 * 64];  // [buf][key][hd], swizzled
  __shared__ __align__(16) bf16 Vt[2 * 64 * 64];  // [buf][hd][key], swizzled
  __shared__ __align__(16) bf16 Ps[128 * 64];     // [q row][key], swizzled

  const int t = threadIdx.x, lane = t & 63, w = t >> 6;   // w = 0..7
  const int quad = lane >> 4, l16 = lane & 15;
  const int bh = blockIdx.y;
  const int q0 = blockIdx.x * 128 + w * 16;               // wave's 16 q-rows

  const bf16* qbase = qb + (size_t)bh * (L_ * HD_);
  const bf16* kbase = kb + (size_t)bh * (L_ * HD_);
  const bf16* vbase = vb + (size_t)bh * (HD_ * L_);

  bf16x8 aq[2];
#pragma unroll
  for (int c = 0; c < 2; ++c)
    aq[c] = *(const bf16x8*)&qbase[(q0 + l16) * HD_ + c * 32 + quad * 8];

  const int vr = lane >> 3;
  const int scol = ((lane & 7) ^ vr) * 8;
  const bf16* ksrc = kbase + (w * 8 + vr) * HD_ + scol;   // + kt*4096
  const bf16* vsrc = vbase + (w * 8 + vr) * L_ + scol;    // + kt*64

  const unsigned long long* adjrow = adj + (size_t)(q0 + quad * 4) * 16;

  float l_acc[4] = {0.f, 0.f, 0.f, 0.f};
  f32x4 o_acc[4] = {};

  const int psoff = (quad * 16) ^ ((l16 & 7) << 4);
  const int pswrow = (w * 16 + quad * 4) * 64;

#define STAGE_KV(i1) do {                                  \
    const int bo_ = ((i1) & 1) * 4096;                     \
    gload_lds16(ksrc + (i1) * 4096, &Ks[bo_ + w * 512]);   \
    gload_lds16(vsrc + (i1) * 64,   &Vt[bo_ + w * 512]);   \
  } while (0)

  STAGE_KV(0);

#pragma unroll 1
  for (int i = 0; i < 16; ++i) {
    const int bufo = (i & 1) * 4096;

    unsigned long long wmask[4];
#pragma unroll
    for (int r = 0; r < 4; ++r) wmask[r] = adjrow[r * 16 + i];

    if (i < 15) STAGE_KV(i + 1);

    if (i < 15) asm volatile("s_waitcnt vmcnt(6)" ::: "memory");
    else        asm volatile("s_waitcnt vmcnt(4)" ::: "memory");
    __builtin_amdgcn_s_barrier();

    f32x4 s[4];
#pragma unroll
    for (int nt = 0; nt < 4; ++nt) {
      f32x4 z = {};
#pragma unroll
      for (int c = 0; c < 2; ++c) {
        bf16x8 bk = *(const bf16x8*)&Ks[bufo + (nt * 16 + l16) * 64 +
            ((psoff ^ (c << 6)) >> 1)];
        z = __builtin_amdgcn_mfma_f32_16x16x32_bf16(aq[c], bk, z, 0, 0, 0);
      }
      s[nt] = z;
    }

#pragma unroll
    for (int r = 0; r < 4; ++r) {
      unsigned long long wr = wmask[r] >> l16;
      float pr = 0.f;
#pragma unroll
      for (int nt = 0; nt < 4; ++nt) {
        float sv = s[nt][r];
        if ((wr >> (nt * 16)) & 1ull) sv = -60000.f;  // exp2 -> 0
        float p = EXP2F(sv);
        int colb = (nt * 32 + l16 * 2) ^ (((quad * 4 + r) & 7) << 4);
        Ps[pswrow + r * 64 + (colb >> 1)] = (bf16)p;
        pr += p;
      }
      l_acc[r] += pr;
    }

#pragma unroll
    for (int c = 0; c < 2; ++c) {
      bf16x8 ap = *(const bf16x8*)
          &Ps[(w * 16 + l16) * 64 + ((psoff ^ (c << 6)) >> 1)];
#pragma unroll
      for (int nt = 0; nt < 4; ++nt) {
        bf16x8 bv = *(const bf16x8*)
            &Vt[bufo + (nt * 16 + l16) * 64 + ((psoff ^ (c << 6)) >> 1)];
        o_acc[nt] = __builtin_amdgcn_mfma_f32_16x16x32_bf16(ap, bv, o_acc[nt], 0, 0, 0);
      }
    }
    __builtin_amdgcn_s_barrier();
  }
#undef STAGE_KV

#pragma unroll
  for (int x = 1; x < 16; x <<= 1)
#pragma unroll
    for (int r = 0; r < 4; ++r)
      l_acc[r] += __shfl_xor(l_acc[r], x, 64);

  const int bb = bh >> 4, h = bh & 15;
#pragma unroll
  for (int r = 0; r < 4; ++r) {
    const float inv = l_acc[r] > 0.f ? 1.f / l_acc[r] : 0.f;
    const int qrow = q0 + quad * 4 + r;
    bf16* orow = aout + ((size_t)(bb * L_ + qrow)) * D_ + h * HD_;
#pragma unroll
    for (int nt = 0; nt < 4; ++nt)
      orow[nt * 16 + l16] = (bf16)(o_acc[nt][r] * inv);
  }
}

// ---------------------------------------------------------------------------
extern "C" void kernel_launch(void* const* d_in, const int* in_sizes, int n_in,
                              void* d_out, int out_size, void* d_ws, size_t ws_size,
                              hipStream_t stream) {
  const void* x_raw  = d_in[0];
  const int*  edges  = (const int*)d_in[1];
  const void* wq_raw = d_in[2];
  const void* bq_raw = d_in[3];
  const void* wo_raw = d_in[4];
  const void* bo_raw = d_in[5];

  char* ws = (char*)d_ws;
  unsigned int*        flag = (unsigned int*)ws;              // 4 B
  unsigned long long*  adj  = (unsigned long long*)(ws + 1024);  // 128 KiB
  size_t off = 1024 + 131072;
  bf16* xb    = (bf16*)(ws + off); off += (size_t)BL_ * D_ * 2;        // 8 MiB
  bf16* wqkvb = (bf16*)(ws + off); off += (size_t)3 * D_ * D_ * 2;     // 6 MiB
  bf16* woutb = (bf16*)(ws + off); off += (size_t)D_ * D_ * 2;         // 2 MiB
  float* bqf  = (float*)(ws + off); off += 3 * D_ * 4;                 // 12 KiB
  float* bof  = (float*)(ws + off); off += D_ * 4;                     // 4 KiB
  bf16* qb    = (bf16*)(ws + off); off += (size_t)BH_ * L_ * HD_ * 2;  // 8 MiB
  bf16* kb    = (bf16*)(ws + off); off += (size_t)BH_ * L_ * HD_ * 2;  // 8 MiB
  bf16* vb    = (bf16*)(ws + off); off += (size_t)BH_ * L_ * HD_ * 2;  // 8 MiB
  bf16* abuf  = (bf16*)(ws + off);                                      // 8 MiB

  // 4 nodes: castall zeroes adj+flag; qkv builds adj (balanced).
  k_castall<<<dim3(4098), dim3(256), 0, stream>>>(
      x_raw, wq_raw, wo_raw, bq_raw, bo_raw, adj,
      xb, wqkvb, woutb, bqf, bof, flag);

  k_gemm_qkv<<<dim3(24, 32), dim3(512), 0, stream>>>(
      xb, wqkvb, bqf, edges, adj, qb, kb, vb);
  k_attn<<<dim3(8, 64), dim3(512), 0, stream>>>(qb, kb, vb, adj, abuf);
  k_gemm_out<<<dim3(16, 64), dim3(256), 0, stream>>>(
      abuf, woutb, bof, d_out, flag);
}